// Round 4
// baseline (19.852 us; speedup 1.0000x reference)
//
#include <hip/hip_runtime.h>
#include <hip/hip_bf16.h>

// Problem constants (from reference setup_inputs)
#define XW   65536   // W
#define XC   256     // C
#define XL   512     // LATENT_DIM (output bins)
#define BIN  128     // W / L elements per bin

#define NG    16     // channel groups (16 channels each)
#define NSPAN 32     // w spans
#define SPANW (XW / NSPAN)   // 2048 floats = 8 KB per span

// ---------------- Phase A: streaming conv partials ----------------
// 512 blocks = 16 channel-groups x 32 w-spans; 512 threads each.
// Per channel-step the whole block reads ONE contiguous 8 KB run of one
// channel (fill-kernel-like streaming), accumulating in registers.
// Writes part[g][w] (16 x 65536 floats = 4 MiB) to scratch.
__global__ __launch_bounds__(512) void statspool_phaseA(
    const float* __restrict__ x,     // [B,C,1,W] -- only b=0 read
    const float* __restrict__ cw,    // [1,C]
    float* __restrict__ part)        // [NG][XW]
{
    const int b  = blockIdx.x;
    const int g  = b & (NG - 1);     // channel group
    const int ws = b >> 4;           // w-span 0..31
    const int t  = threadIdx.x;      // 0..511

    const int w0 = ws * SPANW + (t << 2);          // this thread's float4
    const float* xp = x + (size_t)(g * 16) * XW + w0;

    float4 acc = make_float4(0.f, 0.f, 0.f, 0.f);
    #pragma unroll
    for (int cs = 0; cs < 16; ++cs) {
        const float wc = cw[g * 16 + cs];          // wave-uniform -> s_load
        const float4 v = *(const float4*)(xp + (size_t)cs * XW);
        acc.x = fmaf(wc, v.x, acc.x);
        acc.y = fmaf(wc, v.y, acc.y);
        acc.z = fmaf(wc, v.z, acc.z);
        acc.w = fmaf(wc, v.w, acc.w);
    }
    *(float4*)(part + (size_t)g * XW + w0) = acc;  // contiguous 8 KB/block
}

// ---------------- Phase B: combine partials, per-bin stats ----------------
// One block per bin (512 x 256 threads). Reads part[16][l*128 .. +128],
// sums over groups, adds bias, reduces mean / mean-of-squares, writes out[l].
__global__ __launch_bounds__(256) void statspool_phaseB(
    const float* __restrict__ part,  // [NG][XW]
    const float* __restrict__ cb,    // [1]
    const float* __restrict__ eps,   // [L]
    float* __restrict__ out)         // [1,L]
{
    const int l = blockIdx.x;
    const int t = threadIdx.x;
    const int j  = t & 127;          // w within bin
    const int gh = t >> 7;           // group half 0..1 (8 groups each)

    const float* pp = part + (size_t)gh * 8 * XW + l * BIN + j;
    float s = 0.f;
    #pragma unroll
    for (int g = 0; g < 8; ++g) s += pp[(size_t)g * XW];

    __shared__ float sm[2][BIN];
    sm[gh][j] = s;
    __syncthreads();

    if (t < 64) {
        const float bsv = cb[0];
        const float o0 = sm[0][t]      + sm[1][t]      + bsv;
        const float o1 = sm[0][t + 64] + sm[1][t + 64] + bsv;
        float su = o0 + o1;
        float sq = fmaf(o0, o0, o1 * o1);
        #pragma unroll
        for (int off = 32; off; off >>= 1) {
            su += __shfl_down(su, off);
            sq += __shfl_down(sq, off);
        }
        if (t == 0) {
            const float inv  = 1.0f / (float)BIN;
            const float mean = su * inv;
            const float msq  = sq * inv;
            const float var  = fmaxf(msq - mean * mean, 0.0f);
            out[l] = fmaf(sqrtf(var), eps[l], mean);
        }
    }
}

// ---------------- Fallback (round-1 single kernel) ----------------
__global__ __launch_bounds__(256) void statspool_fallback(
    const float* __restrict__ x, const float* __restrict__ cw,
    const float* __restrict__ cb, const float* __restrict__ eps,
    float* __restrict__ out)
{
    const int l  = blockIdx.x;
    const int t  = threadIdx.x;
    const int wi = t & 63;
    const int cg = t >> 6;

    const int w0 = l * BIN + (wi << 1);
    const float* xp = x + (size_t)cg * 64 * XW + w0;

    float a0 = 0.f, a1 = 0.f;
    #pragma unroll 8
    for (int c = 0; c < 64; ++c) {
        const float wc = cw[(cg << 6) + c];
        const float2 v = *(const float2*)(xp + (size_t)c * XW);
        a0 = fmaf(wc, v.x, a0);
        a1 = fmaf(wc, v.y, a1);
    }
    __shared__ float part0[4][64];
    __shared__ float part1[4][64];
    part0[cg][wi] = a0;
    part1[cg][wi] = a1;
    __syncthreads();
    if (t < 64) {
        const float b  = cb[0];
        const float o0 = part0[0][wi] + part0[1][wi] + part0[2][wi] + part0[3][wi] + b;
        const float o1 = part1[0][wi] + part1[1][wi] + part1[2][wi] + part1[3][wi] + b;
        float s  = o0 + o1;
        float sq = fmaf(o0, o0, o1 * o1);
        #pragma unroll
        for (int off = 32; off; off >>= 1) {
            s  += __shfl_down(s,  off);
            sq += __shfl_down(sq, off);
        }
        if (wi == 0) {
            const float inv  = 1.0f / (float)BIN;
            const float mean = s * inv;
            const float msq  = sq * inv;
            const float var  = fmaxf(msq - mean * mean, 0.0f);
            out[l] = fmaf(sqrtf(var), eps[l], mean);
        }
    }
}

extern "C" void kernel_launch(void* const* d_in, const int* in_sizes, int n_in,
                              void* d_out, int out_size, void* d_ws, size_t ws_size,
                              hipStream_t stream) {
    const float* x   = (const float*)d_in[0];   // [8,256,1,65536] f32
    const float* cw  = (const float*)d_in[1];   // [1,256] f32
    const float* cb  = (const float*)d_in[2];   // [1] f32
    const float* eps = (const float*)d_in[3];   // [512] f32
    float* out = (float*)d_out;                 // [1,512] f32

    const size_t need = (size_t)NG * XW * sizeof(float);  // 4 MiB partials
    if (ws_size >= need) {
        float* part = (float*)d_ws;
        statspool_phaseA<<<dim3(NG * NSPAN), dim3(512), 0, stream>>>(x, cw, part);
        statspool_phaseB<<<dim3(XL), dim3(256), 0, stream>>>(part, cb, eps, out);
    } else {
        statspool_fallback<<<dim3(XL), dim3(256), 0, stream>>>(x, cw, cb, eps, out);
    }
}

// Round 6
// 14.789 us; speedup vs baseline: 1.3423x; 1.3423x over previous
//
#include <hip/hip_runtime.h>
#include <hip/hip_bf16.h>

// Problem constants (from reference setup_inputs)
#define XW   65536   // W
#define XC   256     // C
#define XL   512     // LATENT_DIM (output bins)
#define BIN  128     // W / L elements per bin

// Native clang vector type -- __builtin_nontemporal_load requires this
// (HIP_vector_type float2 is rejected).
typedef float f32x2 __attribute__((ext_vector_type(2)));

// Round-1 structure (best so far: 15.9 us) + NON-TEMPORAL x loads.
// One block per output bin l. 256 threads = 4 c-groups x 64 lanes.
// Each lane handles 2 consecutive w's (8B/lane coalesced).
// Only batch 0 of x is ever read (the output depends only on batch 0).
// x data is read exactly once chip-wide -> bypass cache allocation (nt).
__global__ __launch_bounds__(256) void statspool_kernel(
    const float* __restrict__ x,     // [B,C,1,W] -- we read only b=0
    const float* __restrict__ cw,    // [1,C]
    const float* __restrict__ cb,    // [1]
    const float* __restrict__ eps,   // [L]
    float* __restrict__ out)         // [1,L]
{
    const int l  = blockIdx.x;       // bin index 0..511
    const int t  = threadIdx.x;      // 0..255
    const int wi = t & 63;           // lane within wave -> 2 w's
    const int cg = t >> 6;           // c-group 0..3 (64 channels each)

    const int w0 = l * BIN + (wi << 1);
    const float* xp = x + (size_t)cg * 64 * XW + w0;

    float a0 = 0.f, a1 = 0.f;
    #pragma unroll 8
    for (int c = 0; c < 64; ++c) {
        const float wc = cw[(cg << 6) + c];            // wave-uniform -> s_load
        const f32x2 v =
            __builtin_nontemporal_load((const f32x2*)(xp + (size_t)c * XW));
        a0 = fmaf(wc, v.x, a0);
        a1 = fmaf(wc, v.y, a1);
    }

    // Combine the 4 c-group partials per w via LDS (stride-1, conflict-free)
    __shared__ float part0[4][64];
    __shared__ float part1[4][64];
    part0[cg][wi] = a0;
    part1[cg][wi] = a1;
    __syncthreads();

    if (t < 64) {
        const float b  = cb[0];
        const float o0 = part0[0][wi] + part0[1][wi] + part0[2][wi] + part0[3][wi] + b;
        const float o1 = part1[0][wi] + part1[1][wi] + part1[2][wi] + part1[3][wi] + b;
        float s  = o0 + o1;            // partial sum over this lane's 2 w's
        float sq = fmaf(o0, o0, o1 * o1);

        // 64-lane wave reduction
        #pragma unroll
        for (int off = 32; off; off >>= 1) {
            s  += __shfl_down(s,  off);
            sq += __shfl_down(sq, off);
        }

        if (wi == 0) {
            const float inv  = 1.0f / (float)BIN;
            const float mean = s * inv;
            const float msq  = sq * inv;
            const float var  = fmaxf(msq - mean * mean, 0.0f);
            out[l] = fmaf(sqrtf(var), eps[l], mean);
        }
    }
}

extern "C" void kernel_launch(void* const* d_in, const int* in_sizes, int n_in,
                              void* d_out, int out_size, void* d_ws, size_t ws_size,
                              hipStream_t stream) {
    const float* x   = (const float*)d_in[0];   // [8,256,1,65536] f32
    const float* cw  = (const float*)d_in[1];   // [1,256] f32
    const float* cb  = (const float*)d_in[2];   // [1] f32
    const float* eps = (const float*)d_in[3];   // [512] f32
    float* out = (float*)d_out;                 // [1,512] f32

    statspool_kernel<<<dim3(XL), dim3(256), 0, stream>>>(x, cw, cb, eps, out);
}

// Round 7
// 14.503 us; speedup vs baseline: 1.3688x; 1.0197x over previous
//
#include <hip/hip_runtime.h>
#include <hip/hip_bf16.h>

// Problem constants (from reference setup_inputs)
#define XW   65536   // W
#define XC   256     // C
#define XL   512     // LATENT_DIM (output bins)
#define BIN  128     // W / L elements per bin

// Native clang vector type -- __builtin_nontemporal_load requires this.
typedef float f32x4 __attribute__((ext_vector_type(4)));

// Round-2 structure (1024 thr = 32 waves/CU) + NT dwordx4 loads.
// One block per bin. 1024 threads = 32 c-groups (8 channels each) x 32 lanes
// (float4 -> 4 w's each). Only batch 0 of x is read (output depends only on
// batch 0); every byte is read exactly once chip-wide -> non-temporal.
__global__ __launch_bounds__(1024) void statspool_kernel(
    const float* __restrict__ x,     // [B,C,1,W] -- we read only b=0
    const float* __restrict__ cw,    // [1,C]
    const float* __restrict__ cb,    // [1]
    const float* __restrict__ eps,   // [L]
    float* __restrict__ out)         // [1,L]
{
    const int l  = blockIdx.x;       // bin index 0..511
    const int t  = threadIdx.x;      // 0..1023
    const int wi = t & 31;           // lane-in-group -> 4 consecutive w's
    const int cg = t >> 5;           // c-group 0..31 (8 channels each)

    // weights for this thread's 8 channels -> registers
    const float4 wA = *(const float4*)(cw + (cg << 3));
    const float4 wB = *(const float4*)(cw + (cg << 3) + 4);
    const float wgt[8] = {wA.x, wA.y, wA.z, wA.w, wB.x, wB.y, wB.z, wB.w};

    const float* xp = x + (size_t)(cg << 3) * XW + l * BIN + (wi << 2);

    f32x4 acc = {0.f, 0.f, 0.f, 0.f};
    #pragma unroll
    for (int c = 0; c < 8; ++c) {
        const f32x4 v =
            __builtin_nontemporal_load((const f32x4*)(xp + (size_t)c * XW));
        acc.x = fmaf(wgt[c], v.x, acc.x);
        acc.y = fmaf(wgt[c], v.y, acc.y);
        acc.z = fmaf(wgt[c], v.z, acc.z);
        acc.w = fmaf(wgt[c], v.w, acc.w);
    }

    // Stage partials: part[cg][w] flat, w = wi*4 + k. Contiguous b128 writes.
    __shared__ float part[32 * BIN];     // 16 KB
    __shared__ float ob[BIN];            // o values for this bin
    *(f32x4*)(part + (cg << 7) + (wi << 2)) = acc;
    __syncthreads();

    // 128 threads each own one w: sum the 32 c-group partials (stride-1,
    // conflict-free), add bias.
    if (t < BIN) {
        float s = 0.f;
        #pragma unroll
        for (int g = 0; g < 32; ++g) s += part[(g << 7) + t];
        ob[t] = s + cb[0];
    }
    __syncthreads();

    // One wave reduces sum / sum-of-squares over the 128 o's.
    if (t < 64) {
        const float o0 = ob[t];
        const float o1 = ob[t + 64];
        float s  = o0 + o1;
        float sq = fmaf(o0, o0, o1 * o1);
        #pragma unroll
        for (int off = 32; off; off >>= 1) {
            s  += __shfl_down(s,  off);
            sq += __shfl_down(sq, off);
        }
        if (t == 0) {
            const float inv  = 1.0f / (float)BIN;
            const float mean = s * inv;
            const float msq  = sq * inv;
            const float var  = fmaxf(msq - mean * mean, 0.0f);
            out[l] = fmaf(sqrtf(var), eps[l], mean);
        }
    }
}

extern "C" void kernel_launch(void* const* d_in, const int* in_sizes, int n_in,
                              void* d_out, int out_size, void* d_ws, size_t ws_size,
                              hipStream_t stream) {
    const float* x   = (const float*)d_in[0];   // [8,256,1,65536] f32
    const float* cw  = (const float*)d_in[1];   // [1,256] f32
    const float* cb  = (const float*)d_in[2];   // [1] f32
    const float* eps = (const float*)d_in[3];   // [512] f32
    float* out = (float*)d_out;                 // [1,512] f32

    statspool_kernel<<<dim3(XL), dim3(1024), 0, stream>>>(x, cw, cb, eps, out);
}